// Round 2
// baseline (2199.415 us; speedup 1.0000x reference)
//
#include <hip/hip_runtime.h>
#include <cfloat>
#include <cmath>

// NoisyTopKRouter eval-mode: logits = x @ W^T, top-2 + softmax over top-2.
// N=131072, D=2048, E=16. Outputs (concatenated flat in d_out as float32):
//   [0 .. 2N)   topk indices (as float values; ref dtype int64)
//   [2N .. 4N)  gating weights (softmax over the two top logits)
//
// Structure: x staged global->LDS via global_load_lds (width 16, zero-VGPR,
// double-buffered); compute reads x via 16-lane broadcast from LDS.
// lane = expert id within a 16-lane group; each group owns 4 rows.

constexpr int D = 2048;
constexpr int E = 16;
constexpr int BLOCK = 256;          // 4 waves
constexpr int RB = 64;              // rows per block
constexpr int CH = 32;              // d-chunk (floats) per step = 128 B
constexpr int STEPS = D / CH;       // 64

__global__ __launch_bounds__(BLOCK, 8) void router_kernel(
    const float* __restrict__ x, const float* __restrict__ W,
    float* __restrict__ out, int N) {
  __shared__ float lds[2][RB * CH];   // 2 x 8 KB

  const int tid  = threadIdx.x;
  const int lane = tid & 63;
  const int wid  = tid >> 6;          // 0..3
  const int e    = lane & 15;         // expert owned by this lane
  const int G    = wid * 4 + (lane >> 4);   // group id 0..15, owns rows 4G..4G+3
  const int rowbase = blockIdx.x * RB;
  if (rowbase >= N) return;           // uniform per block (grid is exact anyway)

  // --- staging addresses: wave `wid` stages rows [wid*16, wid*16+16) in two
  // issues of 8 rows; lane l covers row (l>>3), col (l&7)*4 of the issue.
  const float* gs0 = x + (size_t)(rowbase + wid * 16 + (lane >> 3)) * D + (lane & 7) * 4;
  const float* gs1 = gs0 + (size_t)8 * D;

  const float* wrow = W + e * D;      // this lane's expert row

  float4 acc[4];
  #pragma unroll
  for (int r = 0; r < 4; ++r) acc[r] = make_float4(0.f, 0.f, 0.f, 0.f);

  // prologue: stage step 0 into buffer 0
  {
    __builtin_amdgcn_global_load_lds(
        (const __attribute__((address_space(1))) void*)gs0,
        (__attribute__((address_space(3))) void*)&lds[0][(wid * 16) * CH], 16, 0, 0);
    __builtin_amdgcn_global_load_lds(
        (const __attribute__((address_space(1))) void*)gs1,
        (__attribute__((address_space(3))) void*)&lds[0][(wid * 16 + 8) * CH], 16, 0, 0);
  }

  for (int s = 0; s < STEPS; ++s) {
    const int cur = s & 1;
    // __syncthreads drains this wave's vmcnt before s_barrier -> after the
    // barrier, buf[cur] is fully staged by all waves, and every wave has
    // finished reading buf[cur^1] (so it is safe to stage into it below).
    __syncthreads();
    if (s + 1 < STEPS) {
      const float* ga = gs0 + (s + 1) * CH;
      const float* gb = gs1 + (s + 1) * CH;
      __builtin_amdgcn_global_load_lds(
          (const __attribute__((address_space(1))) void*)ga,
          (__attribute__((address_space(3))) void*)&lds[cur ^ 1][(wid * 16) * CH], 16, 0, 0);
      __builtin_amdgcn_global_load_lds(
          (const __attribute__((address_space(1))) void*)gb,
          (__attribute__((address_space(3))) void*)&lds[cur ^ 1][(wid * 16 + 8) * CH], 16, 0, 0);
    }
    // compute on buf[cur]: 4 rows x 32 floats for this group, expert `e`.
    const float* wchunk = wrow + s * CH;
    const float* xrow   = &lds[cur][(G * 4) * CH];
    #pragma unroll
    for (int j = 0; j < 8; ++j) {
      const float4 wv = *reinterpret_cast<const float4*>(wchunk + 4 * j);
      #pragma unroll
      for (int r = 0; r < 4; ++r) {
        const float4 xv = *reinterpret_cast<const float4*>(xrow + r * CH + 4 * j);
        acc[r].x = fmaf(xv.x, wv.x, acc[r].x);
        acc[r].y = fmaf(xv.y, wv.y, acc[r].y);
        acc[r].z = fmaf(xv.z, wv.z, acc[r].z);
        acc[r].w = fmaf(xv.w, wv.w, acc[r].w);
      }
    }
  }

  float s_i1 = 0.f, s_i2 = 0.f, s_g1 = 0.f, s_g2 = 0.f;

  #pragma unroll
  for (int r = 0; r < 4; ++r) {
    // pairwise horizontal sum of the 4 component chains (same order as the
    // round-1 kernel, which matched the reference exactly)
    float m1 = (acc[r].x + acc[r].y) + (acc[r].z + acc[r].w);
    int   i1 = e;
    float m2 = -FLT_MAX;
    int   i2 = E;
    // top-2 butterfly across the 16 expert lanes; lowest index wins ties
    #pragma unroll
    for (int mask = 1; mask < 16; mask <<= 1) {
      const float om1 = __shfl_xor(m1, mask);
      const int   oi1 = __shfl_xor(i1, mask);
      const float om2 = __shfl_xor(m2, mask);
      const int   oi2 = __shfl_xor(i2, mask);
      const bool bwin = (om1 > m1) || (om1 == m1 && oi1 < i1);
      const float a1 = bwin ? om1 : m1; const int ai1 = bwin ? oi1 : i1;
      const float l1 = bwin ? m1 : om1; const int li1 = bwin ? i1 : oi1;
      const float a2 = bwin ? om2 : m2; const int ai2 = bwin ? oi2 : i2;
      const bool lwin = (l1 > a2) || (l1 == a2 && li1 < ai2);
      m1 = a1; i1 = ai1;
      m2 = lwin ? l1 : a2; i2 = lwin ? li1 : ai2;
    }
    if (e == r) {   // lane r keeps row r's result for the store below
      const float ex  = expf(m2 - m1);        // m2 <= m1 -> ex in (0,1]
      const float inv = 1.0f / (1.0f + ex);
      s_i1 = (float)i1; s_i2 = (float)i2;
      s_g1 = inv;       s_g2 = ex * inv;
    }
  }

  if (e < 4) {
    const int row = rowbase + G * 4 + e;
    float2* outi = reinterpret_cast<float2*>(out);
    outi[row] = make_float2(s_i1, s_i2);
    float2* outw = reinterpret_cast<float2*>(out + (size_t)N * 2);
    outw[row] = make_float2(s_g1, s_g2);
  }
}

extern "C" void kernel_launch(void* const* d_in, const int* in_sizes, int n_in,
                              void* d_out, int out_size, void* d_ws, size_t ws_size,
                              hipStream_t stream) {
  const float* x = (const float*)d_in[0];
  const float* W = (const float*)d_in[1];
  float* out = (float*)d_out;
  const int N = in_sizes[0] / D;   // 131072
  const int grid = (N + RB - 1) / RB;  // 2048
  router_kernel<<<grid, BLOCK, 0, stream>>>(x, W, out, N);
}

// Round 3
// 1584.554 us; speedup vs baseline: 1.3880x; 1.3880x over previous
//
#include <hip/hip_runtime.h>
#include <cfloat>
#include <cmath>

// NoisyTopKRouter eval-mode: logits = x @ W^T, top-2 + softmax over top-2.
// N=131072, D=2048, E=16. Outputs (concatenated flat in d_out as float32):
//   [0 .. 2N)   topk indices (as float values; ref dtype int64)
//   [2N .. 4N)  gating weights (softmax over the two top logits)
//
// Structure: W (128 KB, L2-resident) staged into LDS in 16x128-float slabs
// (2 barriers per slab, 16 slabs); x (the 1 GB stream) read directly from
// global with 16-lane-broadcast float4 loads — barrier-free within a slab so
// the compiler can keep many loads in flight. lane = expert id within a
// 16-lane group; each group owns 4 rows; acc is only 16 VGPRs.

constexpr int D = 2048;
constexpr int E = 16;
constexpr int BLOCK = 256;          // 4 waves
constexpr int RB = 64;              // rows per block: 16 groups x 4 rows
constexpr int MC = 128;             // macro-chunk width (floats)
constexpr int NMS = D / MC;         // 16 macro-steps
constexpr int WPAD = 132;           // LDS pitch: rows 528 B (16B-aligned), banks e / e+8 pair -> 2-way (free)

__global__ __launch_bounds__(BLOCK, 4) void router_kernel(
    const float* __restrict__ x, const float* __restrict__ W,
    float* __restrict__ out, int N) {
  __shared__ float wlds[E * WPAD];    // 8448 B

  const int tid  = threadIdx.x;
  const int lane = tid & 63;
  const int wid  = tid >> 6;          // 0..3
  const int e    = lane & 15;         // expert owned by this lane
  const int G    = wid * 4 + (lane >> 4);   // group 0..15, owns rows 4G..4G+3
  const int rowbase = blockIdx.x * RB;
  if (rowbase >= N) return;

  const float* __restrict__ xg = x + (size_t)(rowbase + G * 4) * D;

  float4 acc[4];
  #pragma unroll
  for (int r = 0; r < 4; ++r) acc[r] = make_float4(0.f, 0.f, 0.f, 0.f);

  for (int ms = 0; ms < NMS; ++ms) {
    if (ms) __syncthreads();          // all waves done reading previous slab
    // cooperative stage of W[:, ms*MC .. +MC): 512 float4, 2 per thread
    #pragma unroll
    for (int k = 0; k < 2; ++k) {
      const int f   = tid + k * 256;  // float4 index 0..511
      const int row = f >> 5;         // 32 float4 per row
      const int c4  = f & 31;
      const float4 v = *reinterpret_cast<const float4*>(W + row * D + ms * MC + c4 * 4);
      *reinterpret_cast<float4*>(&wlds[row * WPAD + c4 * 4]) = v;
    }
    __syncthreads();                  // slab staged

    const float* xc = xg + ms * MC;
    #pragma unroll
    for (int j = 0; j < MC / 4; ++j) {   // 32 iterations, barrier-free
      const float4 wv = *reinterpret_cast<const float4*>(&wlds[e * WPAD + 4 * j]);
      #pragma unroll
      for (int r = 0; r < 4; ++r) {
        const float4 xv = *reinterpret_cast<const float4*>(xc + (size_t)r * D + 4 * j);
        acc[r].x = fmaf(xv.x, wv.x, acc[r].x);
        acc[r].y = fmaf(xv.y, wv.y, acc[r].y);
        acc[r].z = fmaf(xv.z, wv.z, acc[r].z);
        acc[r].w = fmaf(xv.w, wv.w, acc[r].w);
      }
    }
  }

  float s_i1 = 0.f, s_i2 = 0.f, s_g1 = 0.f, s_g2 = 0.f;

  #pragma unroll
  for (int r = 0; r < 4; ++r) {
    // pairwise horizontal sum of the 4 component chains (same order as the
    // round-1/2 kernels, which matched the reference exactly)
    float m1 = (acc[r].x + acc[r].y) + (acc[r].z + acc[r].w);
    int   i1 = e;
    float m2 = -FLT_MAX;
    int   i2 = E;
    // top-2 butterfly across the 16 expert lanes; lowest index wins ties
    #pragma unroll
    for (int mask = 1; mask < 16; mask <<= 1) {
      const float om1 = __shfl_xor(m1, mask);
      const int   oi1 = __shfl_xor(i1, mask);
      const float om2 = __shfl_xor(m2, mask);
      const int   oi2 = __shfl_xor(i2, mask);
      const bool bwin = (om1 > m1) || (om1 == m1 && oi1 < i1);
      const float a1 = bwin ? om1 : m1; const int ai1 = bwin ? oi1 : i1;
      const float l1 = bwin ? m1 : om1; const int li1 = bwin ? i1 : oi1;
      const float a2 = bwin ? om2 : m2; const int ai2 = bwin ? oi2 : i2;
      const bool lwin = (l1 > a2) || (l1 == a2 && li1 < ai2);
      m1 = a1; i1 = ai1;
      m2 = lwin ? l1 : a2; i2 = lwin ? li1 : ai2;
    }
    if (e == r) {   // lane r keeps row r's result for the store below
      const float ex  = expf(m2 - m1);        // m2 <= m1 -> ex in (0,1]
      const float inv = 1.0f / (1.0f + ex);
      s_i1 = (float)i1; s_i2 = (float)i2;
      s_g1 = inv;       s_g2 = ex * inv;
    }
  }

  if (e < 4) {
    const int row = rowbase + G * 4 + e;
    float2* outi = reinterpret_cast<float2*>(out);
    outi[row] = make_float2(s_i1, s_i2);
    float2* outw = reinterpret_cast<float2*>(out + (size_t)N * 2);
    outw[row] = make_float2(s_g1, s_g2);
  }
}

extern "C" void kernel_launch(void* const* d_in, const int* in_sizes, int n_in,
                              void* d_out, int out_size, void* d_ws, size_t ws_size,
                              hipStream_t stream) {
  const float* x = (const float*)d_in[0];
  const float* W = (const float*)d_in[1];
  float* out = (float*)d_out;
  const int N = in_sizes[0] / D;   // 131072
  const int grid = (N + RB - 1) / RB;  // 2048
  router_kernel<<<grid, BLOCK, 0, stream>>>(x, W, out, N);
}